// Round 4
// baseline (523.111 us; speedup 1.0000x reference)
//
#include <hip/hip_runtime.h>
#include <math.h>

typedef int intx4 __attribute__((ext_vector_type(4)));
typedef int intx8 __attribute__((ext_vector_type(8)));
typedef float floatx4 __attribute__((ext_vector_type(4)));

#define N_ROWS 8192
#define KDIM 1024

// E8M0 scale bytes: 123 -> 2^-4 per side (data pre-scaled by 2^4 each side)
#define SCALE_WORD 0x7B7B7B7B

// order-preserving float->int encoding for atomicMax
__device__ __forceinline__ int fenc(float f) {
  int i = __float_as_int(f);
  return i >= 0 ? i : (i ^ 0x7fffffff);
}
__device__ __forceinline__ float fdec(int e) {
  int b = e >= 0 ? e : (e ^ 0x7fffffff);
  return __int_as_float(b);
}

// Fused: one block per row of ex (b < 8192) or ey (b >= 8192).
// Computes 1/||x|| (fp32), writes row normalized*16 as e4m3 via HW cvt,
// inits the max slot.
__global__ __launch_bounds__(256) void normalize_kernel(
    const float* __restrict__ ex, const float* __restrict__ ey,
    unsigned char* __restrict__ exn, unsigned char* __restrict__ eyn,
    int* __restrict__ rowmax, int* __restrict__ colmax) {
  const int b = blockIdx.x;
  const int tid = threadIdx.x;
  const float* x;
  unsigned char* out;
  int* mslot;
  int row;
  if (b < N_ROWS) {
    x = ex; out = exn; mslot = rowmax; row = b;
  } else {
    x = ey; out = eyn; mslot = colmax; row = b - N_ROWS;
  }
  const float4* xr = (const float4*)(x + (size_t)row * KDIM);
  float4 v = xr[tid];  // 256 threads * 4 = 1024 elements
  float ss = v.x * v.x + v.y * v.y + v.z * v.z + v.w * v.w;
#pragma unroll
  for (int off = 32; off > 0; off >>= 1) ss += __shfl_down(ss, off, 64);
  __shared__ float sred[4];
  if ((tid & 63) == 0) sred[tid >> 6] = ss;
  __syncthreads();
  const float total = sred[0] + sred[1] + sred[2] + sred[3];
  const float rs = 16.0f * rsqrtf(fmaxf(total, 1e-24f));  // 2^4 pre-scale
  // gfx950 HW fp8 (OCP e4m3fn) pack: two f32 -> low/high half-word
  int w = __builtin_amdgcn_cvt_pk_fp8_f32(v.x * rs, v.y * rs, 0, false);
  w = __builtin_amdgcn_cvt_pk_fp8_f32(v.z * rs, v.w * rs, w, true);
  ((int*)(out + (size_t)row * KDIM))[tid] = w;
  if (tid == 0) mslot[row] = (int)0x80000000;  // encoded -inf floor
}

// Load a 32-byte fragment as two b128 LDS reads (swizzled slots).
__device__ __forceinline__ intx8 ld32(const unsigned char* base, int oLo, int oHi) {
  const intx4 lo = *(const intx4*)(base + oLo);
  const intx4 hi = *(const intx4*)(base + oHi);
  intx8 r;
  r[0] = lo[0]; r[1] = lo[1]; r[2] = lo[2]; r[3] = lo[3];
  r[4] = hi[0]; r[5] = hi[1]; r[6] = hi[2]; r[7] = hi[3];
  return r;
}

// 128x128 tile GEMM (A @ B^T, row-major K-contiguous e4m3) using MX-scaled
// mfma_scale_f32_16x16x128_f8f6f4, fused with row/col max reduction.
//
// LDS: 128 rows x 128 B per matrix per K-step; 16-B chunk c of row r stored
// at slot c ^ (r&7) (same swizzle on staging source and fragment reads, so
// operand content at (quad, byte) is l16-independent — identical for A and B,
// which is all dot-product pairing requires; verified correct in round 3).
//
// __launch_bounds__(256, 2): cap total regs at 256 so 2 blocks/CU are
// resident (round 3's 244+acc regs collapsed to 1 block/CU and serialized
// the stage->barrier->compute chain). bF is transient (8 regs live) to fit.
__global__ __launch_bounds__(256, 2) void gemm_max_kernel(
    const unsigned char* __restrict__ A, const unsigned char* __restrict__ B,
    int* __restrict__ rowmax, int* __restrict__ colmax) {
  constexpr int TM = 128, BK = 128, K = KDIM;
  __shared__ __align__(16) unsigned char sA[TM * BK];  // 16 KB
  __shared__ __align__(16) unsigned char sB[TM * BK];  // 16 KB

  const int bm = blockIdx.x, bn = blockIdx.y;
  const int tid = threadIdx.x;
  const int lane = tid & 63, wave = tid >> 6;
  const int wm = wave >> 1, wn = wave & 1;  // 2x2 waves of 64x64
  const int quad = lane >> 4, l16 = lane & 15;
  const int sw7 = l16 & 7;
  const int oLo = ((2 * quad + 0) ^ sw7) << 4;  // swizzled slot byte offsets
  const int oHi = ((2 * quad + 1) ^ sw7) << 4;

  const char* Ab = (const char*)(A + (size_t)bm * TM * K);
  const char* Bb = (const char*)(B + (size_t)bn * TM * K);

  floatx4 acc[4][4] = {};

  // Staging geometry: wave w stages rows w*32..w*32+31 of each tile.
  // One global_load_lds: 64 lanes x 16 B = 8 rows (8 chunk-lanes per row).
  const int r0 = wave * 32 + (lane >> 3);                 // lane's dest row (it=0)
  const int src_c16 = (((lane & 7) ^ (lane >> 3)) << 4);  // swizzled source chunk
  const char* gA = Ab + (size_t)r0 * K + src_c16;
  const char* gB = Bb + (size_t)r0 * K + src_c16;
  const int obase_w = wave * 4096;

  for (int k0 = 0; k0 < K; k0 += BK) {
#pragma unroll
    for (int it = 0; it < 4; ++it) {
      const int obase = obase_w + it * 1024;                // wave-uniform base
      const size_t gofs = (size_t)k0 + (size_t)it * 8 * K;  // +8 rows per it
      __builtin_amdgcn_global_load_lds(
          (__attribute__((address_space(1))) void*)(gA + gofs),
          (__attribute__((address_space(3))) void*)(((char*)sA) + obase), 16, 0, 0);
      __builtin_amdgcn_global_load_lds(
          (__attribute__((address_space(1))) void*)(gB + gofs),
          (__attribute__((address_space(3))) void*)(((char*)sB) + obase), 16, 0, 0);
    }
    __syncthreads();

    // aF persistent (32 regs); bF transient (8 regs live at a time).
    intx8 aF[4];
    const unsigned char* aBase = &sA[(wm * 64 + l16) * BK];
#pragma unroll
    for (int mi = 0; mi < 4; ++mi)
      aF[mi] = ld32(aBase + mi * 16 * BK, oLo, oHi);

    const unsigned char* bBase = &sB[(wn * 64 + l16) * BK];
#pragma unroll
    for (int ni = 0; ni < 4; ++ni) {
      const intx8 bF = ld32(bBase + ni * 16 * BK, oLo, oHi);
#pragma unroll
      for (int mi = 0; mi < 4; ++mi)
        acc[mi][ni] = __builtin_amdgcn_mfma_scale_f32_16x16x128_f8f6f4(
            aF[mi], bF, acc[mi][ni],
            0 /*cbsz: fp8*/, 0 /*blgp: fp8*/,
            0, SCALE_WORD, 0, SCALE_WORD);
    }
    __syncthreads();
  }

  // C/D layout (16x16 shapes, dtype-independent): col = lane&15, row = quad*4+reg.
#pragma unroll
  for (int mi = 0; mi < 4; ++mi) {
#pragma unroll
    for (int r = 0; r < 4; ++r) {
      float v = fmaxf(fmaxf(acc[mi][0][r], acc[mi][1][r]),
                      fmaxf(acc[mi][2][r], acc[mi][3][r]));
#pragma unroll
      for (int m = 1; m < 16; m <<= 1) v = fmaxf(v, __shfl_xor(v, m, 64));
      if (l16 == 0) {
        const int grow = bm * TM + wm * 64 + mi * 16 + quad * 4 + r;
        atomicMax(&rowmax[grow], fenc(v));
      }
    }
  }
#pragma unroll
  for (int ni = 0; ni < 4; ++ni) {
    float v = -3.402823466e38f;
#pragma unroll
    for (int mi = 0; mi < 4; ++mi)
#pragma unroll
      for (int r = 0; r < 4; ++r) v = fmaxf(v, acc[mi][ni][r]);
    v = fmaxf(v, __shfl_xor(v, 16, 64));
    v = fmaxf(v, __shfl_xor(v, 32, 64));
    if (quad == 0) {
      const int gcol = bn * TM + wn * 64 + ni * 16 + l16;
      atomicMax(&colmax[gcol], fenc(v));
    }
  }
}

__global__ __launch_bounds__(1024) void finalize_kernel(
    const int* __restrict__ rowmax, const int* __restrict__ colmax,
    float* __restrict__ out) {
  const int tid = threadIdx.x;
  float s1 = 0.f, s2 = 0.f;
  for (int i = tid; i < N_ROWS; i += 1024) {
    s1 += 1.0f - fdec(rowmax[i]);
    s2 += 1.0f - fdec(colmax[i]);
  }
#pragma unroll
  for (int off = 32; off > 0; off >>= 1) {
    s1 += __shfl_down(s1, off, 64);
    s2 += __shfl_down(s2, off, 64);
  }
  __shared__ float r1[16], r2[16];
  if ((tid & 63) == 0) {
    r1[tid >> 6] = s1;
    r2[tid >> 6] = s2;
  }
  __syncthreads();
  if (tid == 0) {
    const double SIGMA = 0.3;
    const double H_CONST = 0.5 * log(2.0 * 3.14159265358979323846 * SIGMA * SIGMA) + 0.5;
    const float HS = (float)(H_CONST / SIGMA);
    float a1 = 0.f, a2 = 0.f;
#pragma unroll
    for (int w = 0; w < 16; ++w) {
      a1 += r1[w];
      a2 += r2[w];
    }
    out[0] = HS * a1;
    out[1] = HS * a2;
  }
}

extern "C" void kernel_launch(void* const* d_in, const int* in_sizes, int n_in,
                              void* d_out, int out_size, void* d_ws, size_t ws_size,
                              hipStream_t stream) {
  const float* ex = (const float*)d_in[0];
  const float* ey = (const float*)d_in[1];
  float* out = (float*)d_out;
  char* ws = (char*)d_ws;

  unsigned char* exn = (unsigned char*)ws;                                   // 8 MB
  unsigned char* eyn = (unsigned char*)(ws + (size_t)N_ROWS * KDIM);         // 8 MB
  int* rowmax = (int*)(ws + (size_t)N_ROWS * KDIM * 2);                      // 32 KB
  int* colmax = rowmax + N_ROWS;                                             // 32 KB

  normalize_kernel<<<2 * N_ROWS, 256, 0, stream>>>(ex, ey, exn, eyn, rowmax, colmax);
  gemm_max_kernel<<<dim3(64, 64), 256, 0, stream>>>(exn, eyn, rowmax, colmax);
  finalize_kernel<<<1, 1024, 0, stream>>>(rowmax, colmax, out);
}

// Round 5
// 269.200 us; speedup vs baseline: 1.9432x; 1.9432x over previous
//
#include <hip/hip_runtime.h>
#include <math.h>

typedef int intx4 __attribute__((ext_vector_type(4)));
typedef int intx8 __attribute__((ext_vector_type(8)));
typedef float floatx4 __attribute__((ext_vector_type(4)));

#define N_ROWS 8192
#define KDIM 1024

// E8M0 scale bytes: 123 -> 2^-4 per side (data pre-scaled by 2^4 each side)
#define SCALE_WORD 0x7B7B7B7B

// order-preserving float->int encoding for atomicMax
__device__ __forceinline__ int fenc(float f) {
  int i = __float_as_int(f);
  return i >= 0 ? i : (i ^ 0x7fffffff);
}
__device__ __forceinline__ float fdec(int e) {
  int b = e >= 0 ? e : (e ^ 0x7fffffff);
  return __int_as_float(b);
}

// Fused: one block per row of ex (b < 8192) or ey (b >= 8192).
// Computes 1/||x|| (fp32), writes row normalized*16 as e4m3 via HW cvt,
// inits the max slot.
__global__ __launch_bounds__(256) void normalize_kernel(
    const float* __restrict__ ex, const float* __restrict__ ey,
    unsigned char* __restrict__ exn, unsigned char* __restrict__ eyn,
    int* __restrict__ rowmax, int* __restrict__ colmax) {
  const int b = blockIdx.x;
  const int tid = threadIdx.x;
  const float* x;
  unsigned char* out;
  int* mslot;
  int row;
  if (b < N_ROWS) {
    x = ex; out = exn; mslot = rowmax; row = b;
  } else {
    x = ey; out = eyn; mslot = colmax; row = b - N_ROWS;
  }
  const float4* xr = (const float4*)(x + (size_t)row * KDIM);
  float4 v = xr[tid];  // 256 threads * 4 = 1024 elements
  float ss = v.x * v.x + v.y * v.y + v.z * v.z + v.w * v.w;
#pragma unroll
  for (int off = 32; off > 0; off >>= 1) ss += __shfl_down(ss, off, 64);
  __shared__ float sred[4];
  if ((tid & 63) == 0) sred[tid >> 6] = ss;
  __syncthreads();
  const float total = sred[0] + sred[1] + sred[2] + sred[3];
  const float rs = 16.0f * rsqrtf(fmaxf(total, 1e-24f));  // 2^4 pre-scale
  // gfx950 HW fp8 (OCP e4m3fn) pack: two f32 -> low/high half-word
  int w = __builtin_amdgcn_cvt_pk_fp8_f32(v.x * rs, v.y * rs, 0, false);
  w = __builtin_amdgcn_cvt_pk_fp8_f32(v.z * rs, v.w * rs, w, true);
  ((int*)(out + (size_t)row * KDIM))[tid] = w;
  if (tid == 0) mslot[row] = (int)0x80000000;  // encoded -inf floor
}

// Load a 32-byte fragment as two b128 LDS reads (swizzled slots).
__device__ __forceinline__ intx8 ld32(const unsigned char* base, int oLo, int oHi) {
  const intx4 lo = *(const intx4*)(base + oLo);
  const intx4 hi = *(const intx4*)(base + oHi);
  intx8 r;
  r[0] = lo[0]; r[1] = lo[1]; r[2] = lo[2]; r[3] = lo[3];
  r[4] = hi[0]; r[5] = hi[1]; r[6] = hi[2]; r[7] = hi[3];
  return r;
}

// 128x128 tile GEMM (A @ B^T, row-major K-contiguous e4m3) using MX-scaled
// mfma_scale_f32_16x16x128_f8f6f4, fused with row/col max reduction.
//
// LDS: double-buffered, 128 rows x 128 B per matrix per K-step; 16-B chunk c
// of row r stored at slot c ^ (r&7) (same swizzle on staging source and
// fragment reads — operand content at (quad, byte) is l16-independent,
// identical mapping for A and B; verified correct rounds 3-4).
//
// K-loop shape (the point of this round): ONE barrier per K-step, placed
// BEFORE the next stage issue:
//     stage(buf0); for s: { barrier; stage(buf[s+1]); compute(buf[s]); }
// The compiler's s_waitcnt vmcnt(0) before s_barrier then waits on loads
// issued a full compute phase earlier (~free), instead of round 3's
// stage->barrier->compute which exposed the entire load latency at
// 1 block/CU occupancy. NO forced min-waves: round 4 showed the honest
// register footprint (~244+acc) spills catastrophically if capped at 128.
__global__ __launch_bounds__(256) void gemm_max_kernel(
    const unsigned char* __restrict__ A, const unsigned char* __restrict__ B,
    int* __restrict__ rowmax, int* __restrict__ colmax) {
  constexpr int TM = 128, BK = 128, K = KDIM;
  constexpr int BUF = TM * BK;                          // 16 KB per buffer
  __shared__ __align__(16) unsigned char sA[2 * BUF];   // 32 KB
  __shared__ __align__(16) unsigned char sB[2 * BUF];   // 32 KB

  const int bm = blockIdx.x, bn = blockIdx.y;
  const int tid = threadIdx.x;
  const int lane = tid & 63, wave = tid >> 6;
  const int wm = wave >> 1, wn = wave & 1;  // 2x2 waves of 64x64
  const int quad = lane >> 4, l16 = lane & 15;
  const int sw7 = l16 & 7;
  const int oLo = ((2 * quad + 0) ^ sw7) << 4;  // swizzled slot byte offsets
  const int oHi = ((2 * quad + 1) ^ sw7) << 4;

  const char* Ab = (const char*)(A + (size_t)bm * TM * K);
  const char* Bb = (const char*)(B + (size_t)bn * TM * K);

  floatx4 acc[4][4] = {};

  // Staging geometry: wave w stages rows w*32..w*32+31 of each tile.
  // One global_load_lds: 64 lanes x 16 B = 8 rows (8 chunk-lanes per row).
  const int r0 = wave * 32 + (lane >> 3);                 // lane's dest row (it=0)
  const int src_c16 = (((lane & 7) ^ (lane >> 3)) << 4);  // swizzled source chunk
  const char* gA = Ab + (size_t)r0 * K + src_c16;
  const char* gB = Bb + (size_t)r0 * K + src_c16;
  const int obase_w = wave * 4096;

#define STAGE(buf, k0)                                                         \
  do {                                                                         \
    _Pragma("unroll") for (int it = 0; it < 4; ++it) {                         \
      const int obase = (buf)*BUF + obase_w + it * 1024;                       \
      const size_t gofs = (size_t)(k0) + (size_t)it * 8 * K;                   \
      __builtin_amdgcn_global_load_lds(                                        \
          (__attribute__((address_space(1))) void*)(gA + gofs),                \
          (__attribute__((address_space(3))) void*)(((char*)sA) + obase), 16,  \
          0, 0);                                                               \
      __builtin_amdgcn_global_load_lds(                                        \
          (__attribute__((address_space(1))) void*)(gB + gofs),                \
          (__attribute__((address_space(3))) void*)(((char*)sB) + obase), 16,  \
          0, 0);                                                               \
    }                                                                          \
  } while (0)

  STAGE(0, 0);

#pragma unroll
  for (int step = 0; step < K / BK; ++step) {
    const int cur = step & 1;
    __syncthreads();  // drains cur's loads (issued one compute-phase ago);
                      // also: all waves done reading the buffer we stage next
    if (step + 1 < K / BK) STAGE(cur ^ 1, (step + 1) * BK);

    // aF persistent (32 regs); bF transient.
    intx8 aF[4];
    const unsigned char* aBase = &sA[cur * BUF + (wm * 64 + l16) * BK];
#pragma unroll
    for (int mi = 0; mi < 4; ++mi)
      aF[mi] = ld32(aBase + mi * 16 * BK, oLo, oHi);

    const unsigned char* bBase = &sB[cur * BUF + (wn * 64 + l16) * BK];
#pragma unroll
    for (int ni = 0; ni < 4; ++ni) {
      const intx8 bF = ld32(bBase + ni * 16 * BK, oLo, oHi);
#pragma unroll
      for (int mi = 0; mi < 4; ++mi)
        acc[mi][ni] = __builtin_amdgcn_mfma_scale_f32_16x16x128_f8f6f4(
            aF[mi], bF, acc[mi][ni],
            0 /*cbsz: fp8*/, 0 /*blgp: fp8*/,
            0, SCALE_WORD, 0, SCALE_WORD);
    }
  }
#undef STAGE

  // C/D layout (16x16 shapes, dtype-independent): col = lane&15, row = quad*4+reg.
#pragma unroll
  for (int mi = 0; mi < 4; ++mi) {
#pragma unroll
    for (int r = 0; r < 4; ++r) {
      float v = fmaxf(fmaxf(acc[mi][0][r], acc[mi][1][r]),
                      fmaxf(acc[mi][2][r], acc[mi][3][r]));
#pragma unroll
      for (int m = 1; m < 16; m <<= 1) v = fmaxf(v, __shfl_xor(v, m, 64));
      if (l16 == 0) {
        const int grow = bm * TM + wm * 64 + mi * 16 + quad * 4 + r;
        atomicMax(&rowmax[grow], fenc(v));
      }
    }
  }
#pragma unroll
  for (int ni = 0; ni < 4; ++ni) {
    float v = -3.402823466e38f;
#pragma unroll
    for (int mi = 0; mi < 4; ++mi)
#pragma unroll
      for (int r = 0; r < 4; ++r) v = fmaxf(v, acc[mi][ni][r]);
    v = fmaxf(v, __shfl_xor(v, 16, 64));
    v = fmaxf(v, __shfl_xor(v, 32, 64));
    if (quad == 0) {
      const int gcol = bn * TM + wn * 64 + ni * 16 + l16;
      atomicMax(&colmax[gcol], fenc(v));
    }
  }
}

__global__ __launch_bounds__(1024) void finalize_kernel(
    const int* __restrict__ rowmax, const int* __restrict__ colmax,
    float* __restrict__ out) {
  const int tid = threadIdx.x;
  float s1 = 0.f, s2 = 0.f;
  for (int i = tid; i < N_ROWS; i += 1024) {
    s1 += 1.0f - fdec(rowmax[i]);
    s2 += 1.0f - fdec(colmax[i]);
  }
#pragma unroll
  for (int off = 32; off > 0; off >>= 1) {
    s1 += __shfl_down(s1, off, 64);
    s2 += __shfl_down(s2, off, 64);
  }
  __shared__ float r1[16], r2[16];
  if ((tid & 63) == 0) {
    r1[tid >> 6] = s1;
    r2[tid >> 6] = s2;
  }
  __syncthreads();
  if (tid == 0) {
    const double SIGMA = 0.3;
    const double H_CONST = 0.5 * log(2.0 * 3.14159265358979323846 * SIGMA * SIGMA) + 0.5;
    const float HS = (float)(H_CONST / SIGMA);
    float a1 = 0.f, a2 = 0.f;
#pragma unroll
    for (int w = 0; w < 16; ++w) {
      a1 += r1[w];
      a2 += r2[w];
    }
    out[0] = HS * a1;
    out[1] = HS * a2;
  }
}

extern "C" void kernel_launch(void* const* d_in, const int* in_sizes, int n_in,
                              void* d_out, int out_size, void* d_ws, size_t ws_size,
                              hipStream_t stream) {
  const float* ex = (const float*)d_in[0];
  const float* ey = (const float*)d_in[1];
  float* out = (float*)d_out;
  char* ws = (char*)d_ws;

  unsigned char* exn = (unsigned char*)ws;                                   // 8 MB
  unsigned char* eyn = (unsigned char*)(ws + (size_t)N_ROWS * KDIM);         // 8 MB
  int* rowmax = (int*)(ws + (size_t)N_ROWS * KDIM * 2);                      // 32 KB
  int* colmax = rowmax + N_ROWS;                                             // 32 KB

  normalize_kernel<<<2 * N_ROWS, 256, 0, stream>>>(ex, ey, exn, eyn, rowmax, colmax);
  gemm_max_kernel<<<dim3(64, 64), 256, 0, stream>>>(exn, eyn, rowmax, colmax);
  finalize_kernel<<<1, 1024, 0, stream>>>(rowmax, colmax, out);
}

// Round 6
// 204.883 us; speedup vs baseline: 2.5532x; 1.3139x over previous
//
#include <hip/hip_runtime.h>
#include <math.h>

typedef int intx4 __attribute__((ext_vector_type(4)));
typedef int intx8 __attribute__((ext_vector_type(8)));
typedef float floatx4 __attribute__((ext_vector_type(4)));

#define N_ROWS 8192
#define KDIM 1024

// E8M0 scale bytes: 123 -> 2^-4 per side (data pre-scaled by 2^4 each side)
#define SCALE_WORD 0x7B7B7B7B

// order-preserving float->int encoding for atomicMax
__device__ __forceinline__ int fenc(float f) {
  int i = __float_as_int(f);
  return i >= 0 ? i : (i ^ 0x7fffffff);
}
__device__ __forceinline__ float fdec(int e) {
  int b = e >= 0 ? e : (e ^ 0x7fffffff);
  return __int_as_float(b);
}

// Fused: one block per row of ex (b < 8192) or ey (b >= 8192).
// Computes 1/||x|| (fp32), writes row normalized*16 as e4m3 via HW cvt,
// inits the max slot.
__global__ __launch_bounds__(256) void normalize_kernel(
    const float* __restrict__ ex, const float* __restrict__ ey,
    unsigned char* __restrict__ exn, unsigned char* __restrict__ eyn,
    int* __restrict__ rowmax, int* __restrict__ colmax) {
  const int b = blockIdx.x;
  const int tid = threadIdx.x;
  const float* x;
  unsigned char* out;
  int* mslot;
  int row;
  if (b < N_ROWS) {
    x = ex; out = exn; mslot = rowmax; row = b;
  } else {
    x = ey; out = eyn; mslot = colmax; row = b - N_ROWS;
  }
  const float4* xr = (const float4*)(x + (size_t)row * KDIM);
  float4 v = xr[tid];  // 256 threads * 4 = 1024 elements
  float ss = v.x * v.x + v.y * v.y + v.z * v.z + v.w * v.w;
#pragma unroll
  for (int off = 32; off > 0; off >>= 1) ss += __shfl_down(ss, off, 64);
  __shared__ float sred[4];
  if ((tid & 63) == 0) sred[tid >> 6] = ss;
  __syncthreads();
  const float total = sred[0] + sred[1] + sred[2] + sred[3];
  const float rs = 16.0f * rsqrtf(fmaxf(total, 1e-24f));  // 2^4 pre-scale
  // gfx950 HW fp8 (OCP e4m3fn) pack: two f32 -> low/high half-word
  int w = __builtin_amdgcn_cvt_pk_fp8_f32(v.x * rs, v.y * rs, 0, false);
  w = __builtin_amdgcn_cvt_pk_fp8_f32(v.z * rs, v.w * rs, w, true);
  ((int*)(out + (size_t)row * KDIM))[tid] = w;
  if (tid == 0) mslot[row] = (int)0x80000000;  // encoded -inf floor
}

// Load a 32-byte fragment as two b128 LDS reads (swizzled slots).
__device__ __forceinline__ intx8 ld32(const unsigned char* base, int oLo, int oHi) {
  const intx4 lo = *(const intx4*)(base + oLo);
  const intx4 hi = *(const intx4*)(base + oHi);
  intx8 r;
  r[0] = lo[0]; r[1] = lo[1]; r[2] = lo[2]; r[3] = lo[3];
  r[4] = hi[0]; r[5] = hi[1]; r[6] = hi[2]; r[7] = hi[3];
  return r;
}

// 128x128 tile GEMM (A @ B^T, row-major K-contiguous e4m3) using MX-scaled
// mfma_scale_f32_16x16x128_f8f6f4, fused with row/col max reduction.
//
// K-loop (this round's point): AITER-style buffer_load->VGPR->ds_write
// pipeline. global_load_lds cannot pipeline: s_waitcnt is address-blind, so
// any ds_read after staging forces a vmcnt(0) drain (rounds 3/5 identical
// 181 us proved it). Here the only vmcnt wait is the data dependence of the
// ds_write on the loaded regs, which lands AFTER the compute phase:
//   LOAD(tile s+1); COMPUTE(buf s&1); WRITE(buf (s+1)&1); barrier
// One barrier per step; at the barrier vmcnt is already drained (loads were
// consumed by the writes), so its implicit vmcnt(0)/lgkmcnt(0) is ~free.
//
// LDS layout: identical to the verified r3/r5 layout. 16-B chunk c of row r
// at slot c ^ (r&7). ds_write dest is linear (lane*16 -> conflict-free);
// each lane LOADS the swizzled global chunk (same gA/gB addressing as the
// verified global_load_lds version). Fragment reads unchanged.
__global__ __launch_bounds__(256) void gemm_max_kernel(
    const unsigned char* __restrict__ A, const unsigned char* __restrict__ B,
    int* __restrict__ rowmax, int* __restrict__ colmax) {
  constexpr int TM = 128, BK = 128, K = KDIM;
  constexpr int BUF = TM * BK;                          // 16 KB per buffer
  __shared__ __align__(16) unsigned char sA[2 * BUF];   // 32 KB
  __shared__ __align__(16) unsigned char sB[2 * BUF];   // 32 KB

  const int bm = blockIdx.x, bn = blockIdx.y;
  const int tid = threadIdx.x;
  const int lane = tid & 63, wave = tid >> 6;
  const int wm = wave >> 1, wn = wave & 1;  // 2x2 waves of 64x64
  const int quad = lane >> 4, l16 = lane & 15;
  const int sw7 = l16 & 7;
  const int oLo = ((2 * quad + 0) ^ sw7) << 4;  // swizzled slot byte offsets
  const int oHi = ((2 * quad + 1) ^ sw7) << 4;

  const char* Ab = (const char*)(A + (size_t)bm * TM * K);
  const char* Bb = (const char*)(B + (size_t)bn * TM * K);

  floatx4 acc[4][4] = {};

  // Staging geometry: wave w stages rows w*32..w*32+31 of each tile; one
  // instruction covers 8 rows (8 chunk-lanes per row), 4 iterations each.
  const int r0 = wave * 32 + (lane >> 3);                 // lane's row (it=0)
  const int src_c16 = (((lane & 7) ^ (lane >> 3)) << 4);  // swizzled src chunk
  const char* gA = Ab + (size_t)r0 * K + src_c16;
  const char* gB = Bb + (size_t)r0 * K + src_c16;
  unsigned char* wA = sA + wave * 4096 + lane * 16;  // linear dest (+buf,+it*1024)
  unsigned char* wB = sB + wave * 4096 + lane * 16;

  intx4 pf[8];  // prefetch regs: 4 A-chunks + 4 B-chunks (32 VGPRs)

#define LOADT(k0)                                                     \
  do {                                                                \
    _Pragma("unroll") for (int it = 0; it < 4; ++it) {                \
      pf[it] = *(const intx4*)(gA + (size_t)(k0) + (size_t)it * 8 * K); \
      pf[4 + it] = *(const intx4*)(gB + (size_t)(k0) + (size_t)it * 8 * K); \
    }                                                                 \
  } while (0)

#define WRITET(buf)                                                   \
  do {                                                                \
    _Pragma("unroll") for (int it = 0; it < 4; ++it) {                \
      *(intx4*)(wA + (buf)*BUF + it * 1024) = pf[it];                 \
      *(intx4*)(wB + (buf)*BUF + it * 1024) = pf[4 + it];             \
    }                                                                 \
  } while (0)

#define COMPUTE(cur)                                                  \
  do {                                                                \
    intx8 aF[4];                                                      \
    const unsigned char* aBase = &sA[(cur)*BUF + (wm * 64 + l16) * BK]; \
    _Pragma("unroll") for (int mi = 0; mi < 4; ++mi)                  \
        aF[mi] = ld32(aBase + mi * 16 * BK, oLo, oHi);                \
    const unsigned char* bBase = &sB[(cur)*BUF + (wn * 64 + l16) * BK]; \
    _Pragma("unroll") for (int ni = 0; ni < 4; ++ni) {                \
      const intx8 bF = ld32(bBase + ni * 16 * BK, oLo, oHi);          \
      _Pragma("unroll") for (int mi = 0; mi < 4; ++mi)                \
          acc[mi][ni] = __builtin_amdgcn_mfma_scale_f32_16x16x128_f8f6f4( \
              aF[mi], bF, acc[mi][ni], 0, 0, 0, SCALE_WORD, 0, SCALE_WORD); \
    }                                                                 \
  } while (0)

  LOADT(0);
  WRITET(0);
  __syncthreads();

  // unroll 1: full unroll would let the compiler hoist all 8 prefetch sets
  // (256 regs -> spill, round-4 style catastrophe).
#pragma unroll 1
  for (int step = 0; step < K / BK - 1; ++step) {
    LOADT((step + 1) * BK);   // in flight across the whole compute phase
    COMPUTE(step & 1);
    WRITET((step + 1) & 1);   // vmcnt wait here is data-dependent, post-compute
    __syncthreads();
  }
  COMPUTE((K / BK - 1) & 1);

#undef LOADT
#undef WRITET
#undef COMPUTE

  // C/D layout (16x16 shapes, dtype-independent): col = lane&15, row = quad*4+reg.
#pragma unroll
  for (int mi = 0; mi < 4; ++mi) {
#pragma unroll
    for (int r = 0; r < 4; ++r) {
      float v = fmaxf(fmaxf(acc[mi][0][r], acc[mi][1][r]),
                      fmaxf(acc[mi][2][r], acc[mi][3][r]));
#pragma unroll
      for (int m = 1; m < 16; m <<= 1) v = fmaxf(v, __shfl_xor(v, m, 64));
      if (l16 == 0) {
        const int grow = bm * TM + wm * 64 + mi * 16 + quad * 4 + r;
        atomicMax(&rowmax[grow], fenc(v));
      }
    }
  }
#pragma unroll
  for (int ni = 0; ni < 4; ++ni) {
    float v = -3.402823466e38f;
#pragma unroll
    for (int mi = 0; mi < 4; ++mi)
#pragma unroll
      for (int r = 0; r < 4; ++r) v = fmaxf(v, acc[mi][ni][r]);
    v = fmaxf(v, __shfl_xor(v, 16, 64));
    v = fmaxf(v, __shfl_xor(v, 32, 64));
    if (quad == 0) {
      const int gcol = bn * TM + wn * 64 + ni * 16 + l16;
      atomicMax(&colmax[gcol], fenc(v));
    }
  }
}

__global__ __launch_bounds__(1024) void finalize_kernel(
    const int* __restrict__ rowmax, const int* __restrict__ colmax,
    float* __restrict__ out) {
  const int tid = threadIdx.x;
  float s1 = 0.f, s2 = 0.f;
  for (int i = tid; i < N_ROWS; i += 1024) {
    s1 += 1.0f - fdec(rowmax[i]);
    s2 += 1.0f - fdec(colmax[i]);
  }
#pragma unroll
  for (int off = 32; off > 0; off >>= 1) {
    s1 += __shfl_down(s1, off, 64);
    s2 += __shfl_down(s2, off, 64);
  }
  __shared__ float r1[16], r2[16];
  if ((tid & 63) == 0) {
    r1[tid >> 6] = s1;
    r2[tid >> 6] = s2;
  }
  __syncthreads();
  if (tid == 0) {
    const double SIGMA = 0.3;
    const double H_CONST = 0.5 * log(2.0 * 3.14159265358979323846 * SIGMA * SIGMA) + 0.5;
    const float HS = (float)(H_CONST / SIGMA);
    float a1 = 0.f, a2 = 0.f;
#pragma unroll
    for (int w = 0; w < 16; ++w) {
      a1 += r1[w];
      a2 += r2[w];
    }
    out[0] = HS * a1;
    out[1] = HS * a2;
  }
}

extern "C" void kernel_launch(void* const* d_in, const int* in_sizes, int n_in,
                              void* d_out, int out_size, void* d_ws, size_t ws_size,
                              hipStream_t stream) {
  const float* ex = (const float*)d_in[0];
  const float* ey = (const float*)d_in[1];
  float* out = (float*)d_out;
  char* ws = (char*)d_ws;

  unsigned char* exn = (unsigned char*)ws;                                   // 8 MB
  unsigned char* eyn = (unsigned char*)(ws + (size_t)N_ROWS * KDIM);         // 8 MB
  int* rowmax = (int*)(ws + (size_t)N_ROWS * KDIM * 2);                      // 32 KB
  int* colmax = rowmax + N_ROWS;                                             // 32 KB

  normalize_kernel<<<2 * N_ROWS, 256, 0, stream>>>(ex, ey, exn, eyn, rowmax, colmax);
  gemm_max_kernel<<<dim3(64, 64), 256, 0, stream>>>(exn, eyn, rowmax, colmax);
  finalize_kernel<<<1, 1024, 0, stream>>>(rowmax, colmax, out);
}